// Round 1
// baseline (537.118 us; speedup 1.0000x reference)
//
#include <hip/hip_runtime.h>

// ComplEx scoring + argmax + gather, MI355X (gfx950).
// scores = E @ concat(s_re, s_im);  out = E[argmax(scores)]
// E is 200000 x 512 f32 = 409.6 MB -> memory-bound, target ~6.3 TB/s.

#define N_ENT 200000
#define DIM 512
#define HALF 256

#define BLOCKS 2048
#define TPB 256
#define WAVES_PER_BLOCK (TPB / 64)
#define TOTAL_WAVES (BLOCKS * WAVES_PER_BLOCK)

__global__ __launch_bounds__(TPB) void complex_score_kernel(
    const float* __restrict__ head,
    const float* __restrict__ quest,
    const float* __restrict__ ents,
    float* __restrict__ blk_score,
    int* __restrict__ blk_idx)
{
    __shared__ float s[DIM];

    const int t = threadIdx.x;

    // Build the rotated query vector s (512 floats) once per block.
    if (t < HALF) {
        const float hre = head[t],  him = head[t + HALF];
        const float qre = quest[t], qim = quest[t + HALF];
        s[t]        = hre * qre - him * qim;   // s_re
        s[t + HALF] = hre * qim + him * qre;   // s_im
    }
    __syncthreads();

    const int lane  = t & 63;
    const int wid   = t >> 6;
    const int gwave = blockIdx.x * WAVES_PER_BLOCK + wid;

    // Each lane owns 8 positions of s: [lane*4 .. +3] and [256 + lane*4 .. +3].
    const float4 s0 = *(const float4*)(&s[lane * 4]);
    const float4 s1 = *(const float4*)(&s[HALF + lane * 4]);

    float best = -1e30f;
    int   bidx = 0x7fffffff;

    // One wave per row; rows strided by total wave count. Rows within a wave
    // increase monotonically, so strict '>' keeps the first occurrence on ties.
    for (int row = gwave; row < N_ENT; row += TOTAL_WAVES) {
        const float4* p = (const float4*)(ents + (size_t)row * DIM);
        const float4 a = p[lane];        // bytes 0..1023 of row (coalesced)
        const float4 b = p[64 + lane];   // bytes 1024..2047 (coalesced)

        float acc = a.x * s0.x + a.y * s0.y + a.z * s0.z + a.w * s0.w
                  + b.x * s1.x + b.y * s1.y + b.z * s1.z + b.w * s1.w;

        // Butterfly reduce across the 64-lane wave; all lanes end with the sum.
        #pragma unroll
        for (int off = 32; off > 0; off >>= 1)
            acc += __shfl_xor(acc, off, 64);

        if (acc > best) { best = acc; bidx = row; }
    }

    // Block-level argmax (min index on tie).
    __shared__ float wscore[WAVES_PER_BLOCK];
    __shared__ int   widx[WAVES_PER_BLOCK];
    if (lane == 0) { wscore[wid] = best; widx[wid] = bidx; }
    __syncthreads();

    if (t == 0) {
        float bs = wscore[0];
        int   bi = widx[0];
        #pragma unroll
        for (int i = 1; i < WAVES_PER_BLOCK; ++i) {
            if (wscore[i] > bs || (wscore[i] == bs && widx[i] < bi)) {
                bs = wscore[i];
                bi = widx[i];
            }
        }
        blk_score[blockIdx.x] = bs;
        blk_idx[blockIdx.x]   = bi;
    }
}

__global__ __launch_bounds__(256) void argmax_gather_kernel(
    const float* __restrict__ blk_score,
    const int* __restrict__ blk_idx,
    const float* __restrict__ ents,
    float* __restrict__ out)
{
    __shared__ float ss[256];
    __shared__ int   si[256];

    const int t = threadIdx.x;
    float bs = -1e30f;
    int   bi = 0x7fffffff;

    for (int i = t; i < BLOCKS; i += 256) {
        const float v  = blk_score[i];
        const int   ix = blk_idx[i];
        if (v > bs || (v == bs && ix < bi)) { bs = v; bi = ix; }
    }
    ss[t] = bs;
    si[t] = bi;
    __syncthreads();

    for (int stride = 128; stride > 0; stride >>= 1) {
        if (t < stride) {
            if (ss[t + stride] > ss[t] ||
                (ss[t + stride] == ss[t] && si[t + stride] < si[t])) {
                ss[t] = ss[t + stride];
                si[t] = si[t + stride];
            }
        }
        __syncthreads();
    }

    const int best = si[0];
    // Copy the winning row (512 floats = 128 float4) to d_out.
    if (t < 128) {
        ((float4*)out)[t] = ((const float4*)(ents + (size_t)best * DIM))[t];
    }
}

extern "C" void kernel_launch(void* const* d_in, const int* in_sizes, int n_in,
                              void* d_out, int out_size, void* d_ws, size_t ws_size,
                              hipStream_t stream) {
    const float* head  = (const float*)d_in[0];   // [512]
    const float* quest = (const float*)d_in[1];   // [512]
    const float* ents  = (const float*)d_in[2];   // [200000, 512]
    float* out = (float*)d_out;                   // [512]

    float* blk_score = (float*)d_ws;                                  // [BLOCKS]
    int*   blk_idx   = (int*)((char*)d_ws + BLOCKS * sizeof(float));  // [BLOCKS]

    complex_score_kernel<<<BLOCKS, TPB, 0, stream>>>(head, quest, ents,
                                                     blk_score, blk_idx);
    argmax_gather_kernel<<<1, 256, 0, stream>>>(blk_score, blk_idx, ents, out);
}

// Round 2
// 534.807 us; speedup vs baseline: 1.0043x; 1.0043x over previous
//
#include <hip/hip_runtime.h>

// ComplEx scoring + argmax + gather, MI355X (gfx950).
// scores = E @ concat(s_re, s_im);  out = E[argmax(scores)]
// E is 200000 x 512 f32 = 409.6 MB -> memory-bound, floor ~65 us at 6.3 TB/s.
//
// v2: 4 rows/wave/iter (8 float4 loads in flight, 2x MLP) + hierarchical
// 4-way wave reduce (10 shfl per 4 rows instead of 24), argmax moved to a
// branch-free per-lane update with one cross-lane reduce after the loop.

#define N_ENT 200000
#define DIM 512
#define HALF 256

#define BLOCKS 2048
#define TPB 256
#define WPB (TPB / 64)
#define TOTAL_WAVES (BLOCKS * WPB)          // 8192
#define ROWS_PER_ITER 4
#define SWEEP (TOTAL_WAVES * ROWS_PER_ITER) // 32768 rows per grid sweep

__global__ __launch_bounds__(TPB) void complex_score_kernel(
    const float* __restrict__ head,
    const float* __restrict__ quest,
    const float* __restrict__ ents,
    float* __restrict__ blk_score,
    int* __restrict__ blk_idx)
{
    __shared__ float s[DIM];

    const int t = threadIdx.x;

    // Rotated query vector s (512 floats), once per block.
    if (t < HALF) {
        const float hre = head[t],  him = head[t + HALF];
        const float qre = quest[t], qim = quest[t + HALF];
        s[t]        = hre * qre - him * qim;   // s_re
        s[t + HALF] = hre * qim + him * qre;   // s_im
    }
    __syncthreads();

    const int lane  = t & 63;
    const int wid   = t >> 6;
    const int gwave = blockIdx.x * WPB + wid;

    // Each lane owns 8 positions of s.
    const float4 s0 = *(const float4*)(&s[lane * 4]);
    const float4 s1 = *(const float4*)(&s[HALF + lane * 4]);

    float best = -3.4e38f;
    int   bidx = 0x7fffffff;

    // 4 consecutive rows per wave per iteration. N_ENT % 4 == 0 and base is
    // always a multiple of 4, so 'base < N_ENT' guards all 4 rows.
    for (int base = gwave * ROWS_PER_ITER; base < N_ENT; base += SWEEP) {
        const float4* p = (const float4*)(ents + (size_t)base * DIM); // 128 f4/row

        const float4 a0 = p[lane],       b0 = p[64 + lane];
        const float4 a1 = p[128 + lane], b1 = p[192 + lane];
        const float4 a2 = p[256 + lane], b2 = p[320 + lane];
        const float4 a3 = p[384 + lane], b3 = p[448 + lane];

        float acc0 = a0.x*s0.x + a0.y*s0.y + a0.z*s0.z + a0.w*s0.w
                   + b0.x*s1.x + b0.y*s1.y + b0.z*s1.z + b0.w*s1.w;
        float acc1 = a1.x*s0.x + a1.y*s0.y + a1.z*s0.z + a1.w*s0.w
                   + b1.x*s1.x + b1.y*s1.y + b1.z*s1.z + b1.w*s1.w;
        float acc2 = a2.x*s0.x + a2.y*s0.y + a2.z*s0.z + a2.w*s0.w
                   + b2.x*s1.x + b2.y*s1.y + b2.z*s1.z + b2.w*s1.w;
        float acc3 = a3.x*s0.x + a3.y*s0.y + a3.z*s0.z + a3.w*s0.w
                   + b3.x*s1.x + b3.y*s1.y + b3.z*s1.z + b3.w*s1.w;

        // Hierarchical 4-value wave reduce: 10 shuffles total.
        // Level 1 (xor 1): pair-sum each acc, then interleave by lane parity.
        const float x0 = acc0 + __shfl_xor(acc0, 1, 64);
        const float x1 = acc1 + __shfl_xor(acc1, 1, 64);
        const float x2 = acc2 + __shfl_xor(acc2, 1, 64);
        const float x3 = acc3 + __shfl_xor(acc3, 1, 64);
        const float c01 = (lane & 1) ? x1 : x0;
        const float c23 = (lane & 1) ? x3 : x2;
        // Level 2 (xor 2): same trick -> class = lane & 3.
        const float y01 = c01 + __shfl_xor(c01, 2, 64);
        const float y23 = c23 + __shfl_xor(c23, 2, 64);
        float r = (lane & 2) ? y23 : y01;
        // Shared butterfly over remaining bits; classes stay segregated.
        r += __shfl_xor(r, 4, 64);
        r += __shfl_xor(r, 8, 64);
        r += __shfl_xor(r, 16, 64);
        r += __shfl_xor(r, 32, 64);

        // Lane's value is the full score of row base + (lane&3).
        const int row = base + (lane & 3);
        if (r > best) { best = r; bidx = row; }   // rows increase -> first-hit kept
    }

    // Cross-lane argmax (max score, min index on tie).
    #pragma unroll
    for (int off = 32; off > 0; off >>= 1) {
        const float ob = __shfl_xor(best, off, 64);
        const int   oi = __shfl_xor(bidx, off, 64);
        if (ob > best || (ob == best && oi < bidx)) { best = ob; bidx = oi; }
    }

    // Block-level argmax (min index on tie).
    __shared__ float wscore[WPB];
    __shared__ int   widx[WPB];
    if (lane == 0) { wscore[wid] = best; widx[wid] = bidx; }
    __syncthreads();

    if (t == 0) {
        float bs = wscore[0];
        int   bi = widx[0];
        #pragma unroll
        for (int i = 1; i < WPB; ++i) {
            if (wscore[i] > bs || (wscore[i] == bs && widx[i] < bi)) {
                bs = wscore[i];
                bi = widx[i];
            }
        }
        blk_score[blockIdx.x] = bs;
        blk_idx[blockIdx.x]   = bi;
    }
}

__global__ __launch_bounds__(256) void argmax_gather_kernel(
    const float* __restrict__ blk_score,
    const int* __restrict__ blk_idx,
    const float* __restrict__ ents,
    float* __restrict__ out)
{
    __shared__ float ss[256];
    __shared__ int   si[256];

    const int t = threadIdx.x;
    float bs = -3.4e38f;
    int   bi = 0x7fffffff;

    for (int i = t; i < BLOCKS; i += 256) {
        const float v  = blk_score[i];
        const int   ix = blk_idx[i];
        if (v > bs || (v == bs && ix < bi)) { bs = v; bi = ix; }
    }
    ss[t] = bs;
    si[t] = bi;
    __syncthreads();

    for (int stride = 128; stride > 0; stride >>= 1) {
        if (t < stride) {
            if (ss[t + stride] > ss[t] ||
                (ss[t + stride] == ss[t] && si[t + stride] < si[t])) {
                ss[t] = ss[t + stride];
                si[t] = si[t + stride];
            }
        }
        __syncthreads();
    }

    const int best = si[0];
    if (t < 128) {
        ((float4*)out)[t] = ((const float4*)(ents + (size_t)best * DIM))[t];
    }
}

extern "C" void kernel_launch(void* const* d_in, const int* in_sizes, int n_in,
                              void* d_out, int out_size, void* d_ws, size_t ws_size,
                              hipStream_t stream) {
    const float* head  = (const float*)d_in[0];   // [512]
    const float* quest = (const float*)d_in[1];   // [512]
    const float* ents  = (const float*)d_in[2];   // [200000, 512]
    float* out = (float*)d_out;                   // [512]

    float* blk_score = (float*)d_ws;                                  // [BLOCKS]
    int*   blk_idx   = (int*)((char*)d_ws + BLOCKS * sizeof(float));  // [BLOCKS]

    complex_score_kernel<<<BLOCKS, TPB, 0, stream>>>(head, quest, ents,
                                                     blk_score, blk_idx);
    argmax_gather_kernel<<<1, 256, 0, stream>>>(blk_score, blk_idx, ents, out);
}